// Round 5
// baseline (15125.372 us; speedup 1.0000x reference)
//
#include <hip/hip_runtime.h>
#include <math.h>

#define IN_DIM 1024
#define MEM 1024
#define NNODE 2048
#define GX_COLS 5120   // [i|o|f|z|u] blocks of 1024

// ---- scan configuration ----
#define NWG 128          // persistent workgroups (co-resident on 256 CUs)
#define WGT 512          // 8 waves; wave w owns local dim w
#define DPW 8            // dims per WG  (MEM / NWG)
#define PUBI (NWG * 16)  // ints per parity in a pub buffer (128 WGs x 8 pairs)

typedef int v4i __attribute__((ext_vector_type(4)));

__device__ __forceinline__ float fsig(float x) {
  return __builtin_amdgcn_rcpf(1.f + __expf(-x));
}
__device__ __forceinline__ float ftanh(float x) {
  return 1.f - 2.f * __builtin_amdgcn_rcpf(1.f + __expf(2.f * x));
}

// publish one producer packet (8 (val,tag) pairs = 64B) from a single lane
// as 4 dwordx4 stores. NOTE: inline-asm "v" INPUT constraints require a true
// vector type (ext_vector_type); a 16B struct like int4 is passed indirectly
// and rejected ("indirect register inputs") -- R4 compile failure.
__device__ __forceinline__ void publish8(int* p, const float* s, int tg) {
#pragma unroll
  for (int q = 0; q < 4; ++q) {
    v4i d;
    d.x = __float_as_int(s[2 * q + 0]); d.y = tg;
    d.z = __float_as_int(s[2 * q + 1]); d.w = tg;
    asm volatile("global_store_dwordx4 %0, %1, off sc0 sc1"
                 :: "v"(p + 4 * q), "v"(d) : "memory");
  }
}

// poll one producer's 8 pairs (64B) until all tags match, return the values
__device__ __forceinline__ void poll_pairs(const int* p, int tg,
                                           float4& lo, float4& hi) {
  int4 a, b, c, d;
  do {
    asm volatile(
        "global_load_dwordx4 %0, %4, off sc0 sc1\n\t"
        "global_load_dwordx4 %1, %4, off offset:16 sc0 sc1\n\t"
        "global_load_dwordx4 %2, %4, off offset:32 sc0 sc1\n\t"
        "global_load_dwordx4 %3, %4, off offset:48 sc0 sc1\n\t"
        "s_waitcnt vmcnt(0)"
        : "=v"(a), "=v"(b), "=v"(c), "=v"(d)
        : "v"(p) : "memory");
  } while ((a.y ^ tg) | (a.w ^ tg) | (b.y ^ tg) | (b.w ^ tg) |
           (c.y ^ tg) | (c.w ^ tg) | (d.y ^ tg) | (d.w ^ tg));
  lo = make_float4(__int_as_float(a.x), __int_as_float(a.z),
                   __int_as_float(b.x), __int_as_float(b.z));
  hi = make_float4(__int_as_float(c.x), __int_as_float(c.z),
                   __int_as_float(d.x), __int_as_float(d.z));
}

// ---------------- init: seed the pub buffers ----------------
__global__ void init_ctrl(int* h_pub, int* v_pub) {
  int t = threadIdx.x;
  for (int i = t; i < PUBI / 2; i += blockDim.x) {
    h_pub[2 * i + 0] = 0;            // value 0.0f
    h_pub[2 * i + 1] = 0;            // tag 0 (h(0) seed)
  }
  for (int i = t; i < PUBI / 2; i += blockDim.x) {
    h_pub[PUBI + 2 * i + 0] = 0;
    h_pub[PUBI + 2 * i + 1] = -1;    // parity1 invalid
  }
  for (int i = t; i < PUBI; i += blockDim.x) {
    v_pub[2 * i + 0] = 0;
    v_pub[2 * i + 1] = -1;           // both parities invalid
  }
}

// ---------------- Gx = inputs @ Wx + bx ----------------
__global__ __launch_bounds__(256) void gemm_gx(
    const float* __restrict__ A, const float* __restrict__ B,
    const float* __restrict__ bias, float* __restrict__ C) {
  __shared__ float As[8][128];
  __shared__ float Bs[8][132];
  const int tid = threadIdx.x;
  const int bm = blockIdx.y * 128;
  const int bn = blockIdx.x * 128;
  const int tx = tid & 15;
  const int ty = tid >> 4;
  const int am = tid >> 1;
  const int ak = (tid & 1) * 4;
  const int bk = tid >> 5;
  const int bn4 = (tid & 31) * 4;

  float acc[8][8] = {};
  for (int k0 = 0; k0 < IN_DIM; k0 += 8) {
    float4 av = *(const float4*)&A[(size_t)(bm + am) * IN_DIM + k0 + ak];
    float4 bv = *(const float4*)&B[(size_t)(k0 + bk) * GX_COLS + bn + bn4];
    __syncthreads();
    As[ak + 0][am] = av.x;
    As[ak + 1][am] = av.y;
    As[ak + 2][am] = av.z;
    As[ak + 3][am] = av.w;
    *(float4*)&Bs[bk][bn4] = bv;
    __syncthreads();
#pragma unroll
    for (int kk = 0; kk < 8; ++kk) {
      float4 a0 = *(const float4*)&As[kk][ty * 4];
      float4 a1 = *(const float4*)&As[kk][64 + ty * 4];
      float4 b0 = *(const float4*)&Bs[kk][tx * 4];
      float4 b1 = *(const float4*)&Bs[kk][64 + tx * 4];
      float a[8] = {a0.x, a0.y, a0.z, a0.w, a1.x, a1.y, a1.z, a1.w};
      float b[8] = {b0.x, b0.y, b0.z, b0.w, b1.x, b1.y, b1.z, b1.w};
#pragma unroll
      for (int i = 0; i < 8; ++i)
#pragma unroll
        for (int j = 0; j < 8; ++j) acc[i][j] += a[i] * b[j];
    }
  }
  float4 bias0 = *(const float4*)&bias[bn + tx * 4];
  float4 bias1 = *(const float4*)&bias[bn + 64 + tx * 4];
#pragma unroll
  for (int i = 0; i < 8; ++i) {
    int row = bm + ((i < 4) ? (ty * 4 + i) : (64 + ty * 4 + (i - 4)));
    float4 c0 = {acc[i][0] + bias0.x, acc[i][1] + bias0.y,
                 acc[i][2] + bias0.z, acc[i][3] + bias0.w};
    float4 c1 = {acc[i][4] + bias1.x, acc[i][5] + bias1.y,
                 acc[i][6] + bias1.z, acc[i][7] + bias1.w};
    *(float4*)&C[(size_t)row * GX_COLS + bn + tx * 4] = c0;
    *(float4*)&C[(size_t)row * GX_COLS + bn + 64 + tx * 4] = c1;
  }
}

// ---------------- persistent chain scan ----------------
// R2 structure (proven stable) with ONE change: S2/S4 + the wave-0 publish
// funnel are replaced by "last leader publishes" via an LDS atomic counter.
// Each leader: write share_*[w]; __threadfence_block(); atomicAdd(&cnt,1);
// the leader seeing the phase-final count (16t+7 for v, 16t+15 for h) reads
// all 8 values and issues the 64B packet itself (4x dwordx4 from one lane).
// Release/acquire: every other leader drained its share-write (fence) before
// its add, and LDS is CU-coherent, so the last leader's reads see all 8
// values. NO intra-WG spins (R3 lesson); only the cross-WG global poll spins.
// Barrier audit (2 barriers suffice):
//  - h_lds: waves 1-2 write h(t+1) after passing BARRIER B(t) => all waves
//    arrived B(t) => all finished dotA(t) reads of h(t).
//  - v_lds: waves 3-4 write v(t) after exiting BARRIER A(t) => all waves
//    arrived A(t) => all finished dotB(t-1) reads of v(t-1).
//  - gx_lds parity t&1 (row t) written at loop-top(t) before A(t); readers
//    after A(t). Overwritten row t-2 was last read in phase A(t-2).
//  - share_v(t) read by last leader before B(t); overwritten in phase
//    A(t+1) > B(t). Counter monotone; no reset race.
__global__ __launch_bounds__(WGT) void scan_kernel(
    const float* __restrict__ Wh, const float* __restrict__ bh,
    const float* __restrict__ Wum, const float* __restrict__ bum,
    const float* __restrict__ pic, const float* __restrict__ pfc,
    const float* __restrict__ poc, const float* __restrict__ pzc,
    const float* __restrict__ Gx,
    int* h_pub, int* v_pub,
    float* __restrict__ out) {
  const int wg = blockIdx.x;
  const int tid = threadIdx.x;
  const int w = tid >> 6;    // wave id == owned local dim
  const int ln = tid & 63;
  const int j = wg * DPW + w;
  const bool leader = (ln == 0);

  __shared__ float h_lds[MEM];
  __shared__ float v_lds[MEM];
  __shared__ float gx_lds[2][5 * DPW];   // [parity][gate*8 + dim]
  __shared__ float share_v[DPW];
  __shared__ float share_h[DPW];
  __shared__ int cnt;

  // register-resident weight slices: k = ln*4 + m*256 + e
  float wi[16], wo[16], wf[16], wz[16], wu[16];
#pragma unroll
  for (int m = 0; m < 4; ++m)
#pragma unroll
    for (int e = 0; e < 4; ++e) {
      int k = ln * 4 + m * 256 + e;
      wi[m * 4 + e] = Wh[(size_t)k * 4096 + 0 * MEM + j];
      wo[m * 4 + e] = Wh[(size_t)k * 4096 + 1 * MEM + j];
      wf[m * 4 + e] = Wh[(size_t)k * 4096 + 2 * MEM + j];
      wz[m * 4 + e] = Wh[(size_t)k * 4096 + 3 * MEM + j];
      wu[m * 4 + e] = Wum[(size_t)k * MEM + j];
    }

  float b_i = 0, b_o = 0, b_f = 0, b_z = 0, b_u = 0;
  float p_i = 0, p_f = 0, p_o = 0, p_z = 0;
  if (leader) {
    b_i = bh[0 * MEM + j]; b_o = bh[1 * MEM + j];
    b_f = bh[2 * MEM + j]; b_z = bh[3 * MEM + j];
    b_u = bum[j];
    p_i = pic[j]; p_f = pfc[j]; p_o = poc[j]; p_z = pzc[j];
  }

  // Gx loader: wave 7 lanes 0..39 (never a poller) -- one-row lookahead.
  const bool gxload = (w == 7) && (ln < 5 * DPW);
  const int g_col = (ln >> 3) * MEM + wg * DPW + (ln & 7);
  float gpre = 0.f;
  if (gxload) gpre = Gx[g_col];          // prologue: row 0
  if (tid == 0) cnt = 0;

  float c = 0.f, hmax = -1e30f;
  float i_keep = 0, f_keep = 0, oh_keep = 0, gux_keep = 0;

  for (int t = 0; t < NNODE; ++t) {
    // stage step-t Gx (loaded one iteration ago) + prefetch step t+1
    if (gxload) {
      gx_lds[t & 1][ln] = gpre;
      const int tn = (t + 1 < NNODE) ? (t + 1) : t;
      gpre = Gx[(size_t)tn * GX_COLS + g_col];
    }

    // ---- poll+stage h(t) (waves 1-2), tag == t ----
    if (tid >= 64 && tid < 192) {
      const int idx = tid - 64;  // producer WG
      float4 lo, hi;
      poll_pairs(h_pub + (t & 1) * PUBI + idx * 16, t, lo, hi);
      *(float4*)&h_lds[idx * 8] = lo;
      *(float4*)&h_lds[idx * 8 + 4] = hi;
    }
    __syncthreads();                             // BARRIER A: h_lds+gx ready

    float si = 0, so = 0, sf = 0, sz = 0;
#pragma unroll
    for (int m = 0; m < 4; ++m) {
      float4 hv = *(const float4*)&h_lds[m * 256 + ln * 4];
      const float* hh = (const float*)&hv;
#pragma unroll
      for (int e = 0; e < 4; ++e) {
        si += hh[e] * wi[m * 4 + e]; so += hh[e] * wo[m * 4 + e];
        sf += hh[e] * wf[m * 4 + e]; sz += hh[e] * wz[m * 4 + e];
      }
    }
#pragma unroll
    for (int off = 32; off >= 1; off >>= 1) {
      si += __shfl_down(si, off); so += __shfl_down(so, off);
      sf += __shfl_down(sf, off); sz += __shfl_down(sz, off);
    }
    if (leader) {
      const float* gxr = (const float*)gx_lds[t & 1];
      float gix = gxr[w], gox = gxr[8 + w], gfx = gxr[16 + w];
      float gzx = gxr[24 + w], gux = gxr[32 + w];
      float iv = fsig(gix + si + b_i + p_i * c);
      float fv = fsig(gfx + sf + b_f + p_f * c);
      float zv = fsig(gzx + sz + b_z + p_z * c);
      float vv = zv * ftanh(c);
      i_keep = iv; f_keep = fv; oh_keep = gox + so + b_o; gux_keep = gux;
      ((volatile float*)share_v)[w] = vv;
      __threadfence_block();
      if (atomicAdd(&cnt, 1) == 16 * t + 7) {      // last leader -> publish
        float s[8];
#pragma unroll
        for (int q = 0; q < 8; ++q) s[q] = ((volatile float*)share_v)[q];
        publish8(v_pub + (t & 1) * PUBI + wg * 16, s, t + 1);
      }
    }

    // ---- poll+stage v(t) (waves 3-4), tag == t+1 ----
    if (tid >= 192 && tid < 320) {
      const int idx = tid - 192;
      float4 lo, hi;
      poll_pairs(v_pub + (t & 1) * PUBI + idx * 16, t + 1, lo, hi);
      *(float4*)&v_lds[idx * 8] = lo;
      *(float4*)&v_lds[idx * 8 + 4] = hi;
    }
    __syncthreads();                             // BARRIER B: v_lds ready

    float sm = 0;
#pragma unroll
    for (int m = 0; m < 4; ++m) {
      float4 vv4 = *(const float4*)&v_lds[m * 256 + ln * 4];
      const float* vv = (const float*)&vv4;
#pragma unroll
      for (int e = 0; e < 4; ++e) sm += vv[e] * wu[m * 4 + e];
    }
#pragma unroll
    for (int off = 32; off >= 1; off >>= 1) sm += __shfl_down(sm, off);
    if (leader) {
      float uv = ftanh(gux_keep + sm + b_u);
      float cn = i_keep * uv + f_keep * c;
      float ov = fsig(oh_keep + p_o * cn);
      float hn = ov * ftanh(cn);
      c = cn;
      hmax = fmaxf(hmax, hn);
      ((volatile float*)share_h)[w] = hn;
      __threadfence_block();
      if (atomicAdd(&cnt, 1) == 16 * t + 15) {     // last leader -> publish
        float s[8];
#pragma unroll
        for (int q = 0; q < 8; ++q) s[q] = ((volatile float*)share_h)[q];
        publish8(h_pub + ((t + 1) & 1) * PUBI + wg * 16, s, t + 1);
      }
    }
  }

  if (leader) out[j] = hmax;
}

extern "C" void kernel_launch(void* const* d_in, const int* in_sizes, int n_in,
                              void* d_out, int out_size, void* d_ws, size_t ws_size,
                              hipStream_t stream) {
  const float* inputs = (const float*)d_in[0];
  const float* Wx  = (const float*)d_in[1];
  const float* bx  = (const float*)d_in[2];
  const float* Wh  = (const float*)d_in[3];
  const float* bh  = (const float*)d_in[4];
  const float* Wum = (const float*)d_in[5];
  const float* bum = (const float*)d_in[6];
  const float* pic = (const float*)d_in[7];
  const float* pfc = (const float*)d_in[8];
  const float* poc = (const float*)d_in[9];
  const float* pzc = (const float*)d_in[10];
  float* out = (float*)d_out;

  // ws: Gx (2048*5120 f32) | h_pub (2*PUBI ints) | v_pub (2*PUBI ints)
  float* Gx = (float*)d_ws;
  int* h_pub = (int*)(Gx + (size_t)NNODE * GX_COLS);
  int* v_pub = h_pub + 2 * PUBI;

  init_ctrl<<<1, 256, 0, stream>>>(h_pub, v_pub);
  gemm_gx<<<dim3(GX_COLS / 128, NNODE / 128), 256, 0, stream>>>(inputs, Wx, bx, Gx);
  scan_kernel<<<NWG, WGT, 0, stream>>>(Wh, bh, Wum, bum, pic, pfc, poc, pzc,
                                       Gx, h_pub, v_pub, out);
}

// Round 6
// 7010.570 us; speedup vs baseline: 2.1575x; 2.1575x over previous
//
#include <hip/hip_runtime.h>
#include <math.h>

#define IN_DIM 1024
#define MEM 1024
#define NNODE 2048
#define GX_COLS 5120   // [i|o|f|z|u] blocks of 1024

// ---- scan configuration ----
#define NWG 128        // persistent workgroups (<= 256 CUs -> co-resident)
#define WGT 512        // threads per WG (8 waves); wave w owns local dim w
#define DPW 8          // dims per WG  (MEM / NWG)
#define PUBI (NWG * 16)  // ints per parity in a pub buffer (128 WGs x 8 pairs)

__device__ __forceinline__ float fsig(float x) {
  return __builtin_amdgcn_rcpf(1.f + __expf(-x));
}
__device__ __forceinline__ float ftanh(float x) {
  // tanh(x) = 1 - 2/(exp(2x)+1); saturates correctly for |x| large
  return 1.f - 2.f * __builtin_amdgcn_rcpf(1.f + __expf(2.f * x));
}

// ---- self-validating 8B packets: (float value, int step-tag) ----
// single dwordx2 store => the pair is never torn; no flag, no drain needed.
// INVARIANT (R1+R5 measured): each 64B packet must be published as ONE
// wave-coalesced transaction (8 lanes x 8B in a single instruction).
// Scattering it (R1: 8 waves) or serializing it (R5: 4x16B one lane)
// multiplies the ~0.45us device-scope visibility latency and blows up
// consumer spin time.
__device__ __forceinline__ void store_pair(int* p, float v, int tg) {
  int2 d; d.x = __float_as_int(v); d.y = tg;
  asm volatile("global_store_dwordx2 %0, %1, off sc0 sc1"
               :: "v"(p), "v"(d) : "memory");
}
// poll one producer's 8 pairs (64B) until all tags match, return the values
__device__ __forceinline__ void poll_pairs(const int* p, int tg,
                                           float4& lo, float4& hi) {
  int4 a, b, c, d;
  do {
    asm volatile(
        "global_load_dwordx4 %0, %4, off sc0 sc1\n\t"
        "global_load_dwordx4 %1, %4, off offset:16 sc0 sc1\n\t"
        "global_load_dwordx4 %2, %4, off offset:32 sc0 sc1\n\t"
        "global_load_dwordx4 %3, %4, off offset:48 sc0 sc1\n\t"
        "s_waitcnt vmcnt(0)"
        : "=v"(a), "=v"(b), "=v"(c), "=v"(d)
        : "v"(p) : "memory");
  } while ((a.y ^ tg) | (a.w ^ tg) | (b.y ^ tg) | (b.w ^ tg) |
           (c.y ^ tg) | (c.w ^ tg) | (d.y ^ tg) | (d.w ^ tg));
  lo = make_float4(__int_as_float(a.x), __int_as_float(a.z),
                   __int_as_float(b.x), __int_as_float(b.z));
  hi = make_float4(__int_as_float(c.x), __int_as_float(c.z),
                   __int_as_float(d.x), __int_as_float(d.z));
}

// ---------------- init: seed the pub buffers ----------------
// h parity0 = (0.0, tag 0) [step-0 input]; everything else tag -1.
__global__ void init_ctrl(int* h_pub, int* v_pub) {
  int t = threadIdx.x;
  for (int i = t; i < PUBI / 2; i += blockDim.x) {
    h_pub[2 * i + 0] = 0;            // value 0.0f
    h_pub[2 * i + 1] = 0;            // tag 0
  }
  for (int i = t; i < PUBI / 2; i += blockDim.x) {
    h_pub[PUBI + 2 * i + 0] = 0;
    h_pub[PUBI + 2 * i + 1] = -1;    // parity1 invalid
  }
  for (int i = t; i < PUBI; i += blockDim.x) {
    v_pub[2 * i + 0] = 0;
    v_pub[2 * i + 1] = -1;           // both parities invalid
  }
}

// ---------------- Gx = inputs @ Wx + bx ----------------
// A: 2048x1024, B: 1024x5120, C: 2048x5120. 128x128 tile, 256 thr, 8x8/thr.
__global__ __launch_bounds__(256) void gemm_gx(
    const float* __restrict__ A, const float* __restrict__ B,
    const float* __restrict__ bias, float* __restrict__ C) {
  __shared__ float As[8][128];
  __shared__ float Bs[8][132];
  const int tid = threadIdx.x;
  const int bm = blockIdx.y * 128;
  const int bn = blockIdx.x * 128;
  const int tx = tid & 15;
  const int ty = tid >> 4;
  const int am = tid >> 1;
  const int ak = (tid & 1) * 4;
  const int bk = tid >> 5;
  const int bn4 = (tid & 31) * 4;

  float acc[8][8] = {};
  for (int k0 = 0; k0 < IN_DIM; k0 += 8) {
    float4 av = *(const float4*)&A[(size_t)(bm + am) * IN_DIM + k0 + ak];
    float4 bv = *(const float4*)&B[(size_t)(k0 + bk) * GX_COLS + bn + bn4];
    __syncthreads();
    As[ak + 0][am] = av.x;
    As[ak + 1][am] = av.y;
    As[ak + 2][am] = av.z;
    As[ak + 3][am] = av.w;
    *(float4*)&Bs[bk][bn4] = bv;
    __syncthreads();
#pragma unroll
    for (int kk = 0; kk < 8; ++kk) {
      float4 a0 = *(const float4*)&As[kk][ty * 4];
      float4 a1 = *(const float4*)&As[kk][64 + ty * 4];
      float4 b0 = *(const float4*)&Bs[kk][tx * 4];
      float4 b1 = *(const float4*)&Bs[kk][64 + tx * 4];
      float a[8] = {a0.x, a0.y, a0.z, a0.w, a1.x, a1.y, a1.z, a1.w};
      float b[8] = {b0.x, b0.y, b0.z, b0.w, b1.x, b1.y, b1.z, b1.w};
#pragma unroll
      for (int i = 0; i < 8; ++i)
#pragma unroll
        for (int j = 0; j < 8; ++j) acc[i][j] += a[i] * b[j];
    }
  }
  float4 bias0 = *(const float4*)&bias[bn + tx * 4];
  float4 bias1 = *(const float4*)&bias[bn + 64 + tx * 4];
#pragma unroll
  for (int i = 0; i < 8; ++i) {
    int row = bm + ((i < 4) ? (ty * 4 + i) : (64 + ty * 4 + (i - 4)));
    float4 c0 = {acc[i][0] + bias0.x, acc[i][1] + bias0.y,
                 acc[i][2] + bias0.z, acc[i][3] + bias0.w};
    float4 c1 = {acc[i][4] + bias1.x, acc[i][5] + bias1.y,
                 acc[i][6] + bias1.z, acc[i][7] + bias1.w};
    *(float4*)&C[(size_t)row * GX_COLS + bn + tx * 4] = c0;
    *(float4*)&C[(size_t)row * GX_COLS + bn + 64 + tx * 4] = c1;
  }
}

// ---------------- persistent chain scan ----------------
// R0 structure (4 barriers, funnel publish) with ONE scheduling change:
// the v-publish is moved ahead of the i/o/f dots. Only the z gate is
// needed to form v = z*tanh(c_p), so per step:
//   [poll h][S1][z-dot+reduce][leader: z,v][S2][tid<8 64B publish]
//   [i/o/f dots+reduces  <-- overlapped with v-packet flight ]
//   [poll v][S3][u-dot][S4][tid<8 64B publish h]
// The ~0.8us v-hop flight is now hidden under ~0.3us of i/o/f work.
// Leaders prefetch the NEXT step's 5 Gx scalars (register double-buffer)
// so gzx is never a cold load on the shortened z critical path.
// Barrier-reuse audit under the new order:
//  - h_lds(t): last read = hreg loads right after S1(t) (dots run from
//    registers). Pollers overwrite at t+1 only after passing S4(t) > S2(t),
//    and S2(t) requires every wave's hreg loads done.
//  - v_lds(t): written by waves 3-4 between S2(t) and S3(t); v_lds(t-1)
//    was last read before S4(t-1) < S1(t) < S2(t).
//  - share: v(t) written pre-S2(t), read by tid<8 pre-S3(t); overwritten
//    with h(t) only post-S3(t). h(t) read post-S4(t) by tid<8 (wave 0),
//    overwritten with v(t+1) only after S1(t+1), which needs wave 0's
//    arrival (read precedes it in program order).
__global__ __launch_bounds__(WGT) void scan_kernel(
    const float* __restrict__ Wh, const float* __restrict__ bh,
    const float* __restrict__ Wum, const float* __restrict__ bum,
    const float* __restrict__ pic, const float* __restrict__ pfc,
    const float* __restrict__ poc, const float* __restrict__ pzc,
    const float* __restrict__ Gx,
    int* h_pub, int* v_pub,
    float* __restrict__ out) {
  const int wg = blockIdx.x;
  const int tid = threadIdx.x;
  const int w = tid >> 6;    // wave id == owned local dim
  const int ln = tid & 63;
  const int j = wg * DPW + w;
  const bool leader = (ln == 0);

  __shared__ float h_lds[MEM];
  __shared__ float v_lds[MEM];
  __shared__ float share[DPW];

  // register-resident weight slices: k = ln*4 + m*256 + e
  float wi[16], wo[16], wf[16], wz[16], wu[16];
#pragma unroll
  for (int m = 0; m < 4; ++m)
#pragma unroll
    for (int e = 0; e < 4; ++e) {
      int k = ln * 4 + m * 256 + e;
      wi[m * 4 + e] = Wh[(size_t)k * 4096 + 0 * MEM + j];
      wo[m * 4 + e] = Wh[(size_t)k * 4096 + 1 * MEM + j];
      wf[m * 4 + e] = Wh[(size_t)k * 4096 + 2 * MEM + j];
      wz[m * 4 + e] = Wh[(size_t)k * 4096 + 3 * MEM + j];
      wu[m * 4 + e] = Wum[(size_t)k * MEM + j];
    }

  float b_i = 0, b_o = 0, b_f = 0, b_z = 0, b_u = 0;
  float p_i = 0, p_f = 0, p_o = 0, p_z = 0;
  if (leader) {
    b_i = bh[0 * MEM + j]; b_o = bh[1 * MEM + j];
    b_f = bh[2 * MEM + j]; b_z = bh[3 * MEM + j];
    b_u = bum[j];
    p_i = pic[j]; p_f = pfc[j]; p_o = poc[j]; p_z = pzc[j];
  }

  // leader Gx register double-buffer: g_* = step t (ready), n_* = step t+1
  // (in flight; issued at loop top, a full ~4us before use).
  float g_i = 0, g_o = 0, g_f = 0, g_z = 0, g_u = 0;
  float n_i = 0, n_o = 0, n_f = 0, n_z = 0, n_u = 0;
  if (leader) {
    g_i = Gx[j];           g_o = Gx[MEM + j];     g_f = Gx[2 * MEM + j];
    g_z = Gx[3 * MEM + j]; g_u = Gx[4 * MEM + j];
  }

  float c = 0.f, hmax = -1e30f;
  float i_keep = 0, f_keep = 0, oh_keep = 0, gux_keep = 0;

  for (int t = 0; t < NNODE; ++t) {
    // prefetch next step's Gx scalars (off critical path; lands during step)
    if (leader && t + 1 < NNODE) {
      const float* gx = Gx + (size_t)(t + 1) * GX_COLS;
      n_i = gx[j];           n_o = gx[MEM + j];     n_f = gx[2 * MEM + j];
      n_z = gx[3 * MEM + j]; n_u = gx[4 * MEM + j];
    }

    // ---- poll+stage h(t) (waves 1-2), tag == t ----
    if (tid >= 64 && tid < 192) {
      const int idx = tid - 64;  // producer WG
      float4 lo, hi;
      poll_pairs(h_pub + (t & 1) * PUBI + idx * 16, t, lo, hi);
      *(float4*)&h_lds[idx * 8] = lo;
      *(float4*)&h_lds[idx * 8 + 4] = hi;
    }
    __syncthreads();                             // S1: h_lds ready

    // pull h slice into registers (single read of h_lds per step)
    float hreg[16];
#pragma unroll
    for (int m = 0; m < 4; ++m) {
      float4 hv = *(const float4*)&h_lds[m * 256 + ln * 4];
      hreg[m * 4 + 0] = hv.x; hreg[m * 4 + 1] = hv.y;
      hreg[m * 4 + 2] = hv.z; hreg[m * 4 + 3] = hv.w;
    }

    // ---- z gate first: the only input to v ----
    float sz = 0;
#pragma unroll
    for (int q = 0; q < 16; ++q) sz += hreg[q] * wz[q];
#pragma unroll
    for (int off = 32; off >= 1; off >>= 1) sz += __shfl_down(sz, off);
    if (leader) {
      float zv = fsig(g_z + sz + b_z + p_z * c);
      share[w] = zv * ftanh(c);
    }
    __syncthreads();                             // S2: share has v slice

    if (tid < 8)   // single wave-coalesced 64B publish (invariant!)
      store_pair(v_pub + (t & 1) * PUBI + wg * 16 + tid * 2, share[tid], t + 1);

    // ---- i/o/f dots: overlapped with the v packet's flight ----
    float si = 0, so = 0, sf = 0;
#pragma unroll
    for (int q = 0; q < 16; ++q) {
      si += hreg[q] * wi[q]; so += hreg[q] * wo[q]; sf += hreg[q] * wf[q];
    }
#pragma unroll
    for (int off = 32; off >= 1; off >>= 1) {
      si += __shfl_down(si, off); so += __shfl_down(so, off);
      sf += __shfl_down(sf, off);
    }
    if (leader) {
      i_keep = fsig(g_i + si + b_i + p_i * c);
      f_keep = fsig(g_f + sf + b_f + p_f * c);
      oh_keep = g_o + so + b_o;
      gux_keep = g_u;
    }

    // ---- poll+stage v(t) (waves 3-4), tag == t+1 ----
    if (tid >= 192 && tid < 320) {
      const int idx = tid - 192;
      float4 lo, hi;
      poll_pairs(v_pub + (t & 1) * PUBI + idx * 16, t + 1, lo, hi);
      *(float4*)&v_lds[idx * 8] = lo;
      *(float4*)&v_lds[idx * 8 + 4] = hi;
    }
    __syncthreads();                             // S3: v_lds ready

    float sm = 0;
#pragma unroll
    for (int m = 0; m < 4; ++m) {
      float4 vv4 = *(const float4*)&v_lds[m * 256 + ln * 4];
      const float* vv = (const float*)&vv4;
#pragma unroll
      for (int e = 0; e < 4; ++e) sm += vv[e] * wu[m * 4 + e];
    }
#pragma unroll
    for (int off = 32; off >= 1; off >>= 1) sm += __shfl_down(sm, off);
    if (leader) {
      float uv = ftanh(gux_keep + sm + b_u);
      float cn = i_keep * uv + f_keep * c;
      float ov = fsig(oh_keep + p_o * cn);
      float hn = ov * ftanh(cn);
      c = cn;
      hmax = fmaxf(hmax, hn);
      share[w] = hn;
      // rotate Gx prefetch buffers for next step
      g_i = n_i; g_o = n_o; g_f = n_f; g_z = n_z; g_u = n_u;
    }
    __syncthreads();                             // S4: share has h slice

    if (tid < 8)   // single wave-coalesced 64B publish (invariant!)
      store_pair(h_pub + ((t + 1) & 1) * PUBI + wg * 16 + tid * 2,
                 share[tid], t + 1);
  }

  if (leader) out[j] = hmax;
}

extern "C" void kernel_launch(void* const* d_in, const int* in_sizes, int n_in,
                              void* d_out, int out_size, void* d_ws, size_t ws_size,
                              hipStream_t stream) {
  const float* inputs = (const float*)d_in[0];
  const float* Wx  = (const float*)d_in[1];
  const float* bx  = (const float*)d_in[2];
  const float* Wh  = (const float*)d_in[3];
  const float* bh  = (const float*)d_in[4];
  const float* Wum = (const float*)d_in[5];
  const float* bum = (const float*)d_in[6];
  const float* pic = (const float*)d_in[7];
  const float* pfc = (const float*)d_in[8];
  const float* poc = (const float*)d_in[9];
  const float* pzc = (const float*)d_in[10];
  float* out = (float*)d_out;

  // ws: Gx (2048*5120 f32) | h_pub (2*PUBI ints) | v_pub (2*PUBI ints)
  float* Gx = (float*)d_ws;
  int* h_pub = (int*)(Gx + (size_t)NNODE * GX_COLS);
  int* v_pub = h_pub + 2 * PUBI;

  init_ctrl<<<1, 256, 0, stream>>>(h_pub, v_pub);
  gemm_gx<<<dim3(GX_COLS / 128, NNODE / 128), 256, 0, stream>>>(inputs, Wx, bx, Gx);
  scan_kernel<<<NWG, WGT, 0, stream>>>(Wh, bh, Wum, bum, pic, pfc, poc, pzc,
                                       Gx, h_pub, v_pub, out);
}

// Round 7
// 6883.148 us; speedup vs baseline: 2.1974x; 1.0185x over previous
//
#include <hip/hip_runtime.h>
#include <math.h>

#define IN_DIM 1024
#define MEM 1024
#define NNODE 2048
#define GX_COLS 5120   // [i|o|f|z|u] blocks of 1024

// ---- scan configuration ----
#define NWG 64           // persistent workgroups (halved: straggler tax + poll fan-in)
#define WGT 512          // 8 waves; wave w owns dims 2w (lanes 0-31) and 2w+1 (32-63)
#define DPW 16           // dims per WG  (MEM / NWG)
#define PUBI (NWG * DPW * 2)  // ints per parity in a pub buffer (= 2048, unchanged)

__device__ __forceinline__ float fsig(float x) {
  return __builtin_amdgcn_rcpf(1.f + __expf(-x));
}
__device__ __forceinline__ float ftanh(float x) {
  // tanh(x) = 1 - 2/(exp(2x)+1); saturates correctly for |x| large
  return 1.f - 2.f * __builtin_amdgcn_rcpf(1.f + __expf(2.f * x));
}

// ---- self-validating 8B packets: (float value, int step-tag) ----
// INVARIANT (R1+R5 measured): each producer packet must be published by ONE
// wave-coalesced store instruction (here 16 lanes x 8B = 128B). Scattering
// across waves (R1) or serializing from one lane (R5) multiplies the
// ~0.45us device-scope visibility latency and blows up consumer spins.
__device__ __forceinline__ void store_pair(int* p, float v, int tg) {
  int2 d; d.x = __float_as_int(v); d.y = tg;
  asm volatile("global_store_dwordx2 %0, %1, off sc0 sc1"
               :: "v"(p), "v"(d) : "memory");
}
// poll one 64B half-packet (8 pairs) until all tags match, return the values
__device__ __forceinline__ void poll_pairs(const int* p, int tg,
                                           float4& lo, float4& hi) {
  int4 a, b, c, d;
  do {
    asm volatile(
        "global_load_dwordx4 %0, %4, off sc0 sc1\n\t"
        "global_load_dwordx4 %1, %4, off offset:16 sc0 sc1\n\t"
        "global_load_dwordx4 %2, %4, off offset:32 sc0 sc1\n\t"
        "global_load_dwordx4 %3, %4, off offset:48 sc0 sc1\n\t"
        "s_waitcnt vmcnt(0)"
        : "=v"(a), "=v"(b), "=v"(c), "=v"(d)
        : "v"(p) : "memory");
  } while ((a.y ^ tg) | (a.w ^ tg) | (b.y ^ tg) | (b.w ^ tg) |
           (c.y ^ tg) | (c.w ^ tg) | (d.y ^ tg) | (d.w ^ tg));
  lo = make_float4(__int_as_float(a.x), __int_as_float(a.z),
                   __int_as_float(b.x), __int_as_float(b.z));
  hi = make_float4(__int_as_float(c.x), __int_as_float(c.z),
                   __int_as_float(d.x), __int_as_float(d.z));
}

// ---------------- init: seed the pub buffers ----------------
// h parity0 = (0.0, tag 0) [h(0) seed]; everything else tag -1.
__global__ void init_ctrl(int* h_pub, int* v_pub) {
  int t = threadIdx.x;
  for (int i = t; i < PUBI / 2; i += blockDim.x) {
    h_pub[2 * i + 0] = 0;            // value 0.0f
    h_pub[2 * i + 1] = 0;            // tag 0
  }
  for (int i = t; i < PUBI / 2; i += blockDim.x) {
    h_pub[PUBI + 2 * i + 0] = 0;
    h_pub[PUBI + 2 * i + 1] = -1;    // parity1 invalid
  }
  for (int i = t; i < PUBI; i += blockDim.x) {
    v_pub[2 * i + 0] = 0;
    v_pub[2 * i + 1] = -1;           // both parities invalid
  }
}

// ---------------- Gx = inputs @ Wx + bx ----------------
// A: 2048x1024, B: 1024x5120, C: 2048x5120. 128x128 tile, 256 thr, 8x8/thr.
__global__ __launch_bounds__(256) void gemm_gx(
    const float* __restrict__ A, const float* __restrict__ B,
    const float* __restrict__ bias, float* __restrict__ C) {
  __shared__ float As[8][128];
  __shared__ float Bs[8][132];
  const int tid = threadIdx.x;
  const int bm = blockIdx.y * 128;
  const int bn = blockIdx.x * 128;
  const int tx = tid & 15;
  const int ty = tid >> 4;
  const int am = tid >> 1;
  const int ak = (tid & 1) * 4;
  const int bk = tid >> 5;
  const int bn4 = (tid & 31) * 4;

  float acc[8][8] = {};
  for (int k0 = 0; k0 < IN_DIM; k0 += 8) {
    float4 av = *(const float4*)&A[(size_t)(bm + am) * IN_DIM + k0 + ak];
    float4 bv = *(const float4*)&B[(size_t)(k0 + bk) * GX_COLS + bn + bn4];
    __syncthreads();
    As[ak + 0][am] = av.x;
    As[ak + 1][am] = av.y;
    As[ak + 2][am] = av.z;
    As[ak + 3][am] = av.w;
    *(float4*)&Bs[bk][bn4] = bv;
    __syncthreads();
#pragma unroll
    for (int kk = 0; kk < 8; ++kk) {
      float4 a0 = *(const float4*)&As[kk][ty * 4];
      float4 a1 = *(const float4*)&As[kk][64 + ty * 4];
      float4 b0 = *(const float4*)&Bs[kk][tx * 4];
      float4 b1 = *(const float4*)&Bs[kk][64 + tx * 4];
      float a[8] = {a0.x, a0.y, a0.z, a0.w, a1.x, a1.y, a1.z, a1.w};
      float b[8] = {b0.x, b0.y, b0.z, b0.w, b1.x, b1.y, b1.z, b1.w};
#pragma unroll
      for (int i = 0; i < 8; ++i)
#pragma unroll
        for (int j = 0; j < 8; ++j) acc[i][j] += a[i] * b[j];
    }
  }
  float4 bias0 = *(const float4*)&bias[bn + tx * 4];
  float4 bias1 = *(const float4*)&bias[bn + 64 + tx * 4];
#pragma unroll
  for (int i = 0; i < 8; ++i) {
    int row = bm + ((i < 4) ? (ty * 4 + i) : (64 + ty * 4 + (i - 4)));
    float4 c0 = {acc[i][0] + bias0.x, acc[i][1] + bias0.y,
                 acc[i][2] + bias0.z, acc[i][3] + bias0.w};
    float4 c1 = {acc[i][4] + bias1.x, acc[i][5] + bias1.y,
                 acc[i][6] + bias1.z, acc[i][7] + bias1.w};
    *(float4*)&C[(size_t)row * GX_COLS + bn + tx * 4] = c0;
    *(float4*)&C[(size_t)row * GX_COLS + bn + 64 + tx * 4] = c1;
  }
}

// ---------------- persistent chain scan ----------------
// R6 structure (proven 6642us) rescaled to NWG=64 / 16 dims per WG:
//  - wave w's HALF-WAVES own dims: lanes 0-31 -> dim wg*16+2w,
//    lanes 32-63 -> dim wg*16+2w+1. Width-32 shuffles reduce each half
//    independently (5 levels instead of 6); two leader lanes (0, 32) per
//    wave run the scalar gate chains in parallel.
//  - publish: tid<16, one wave-coalesced 128B store (invariant).
//  - polls: 64 producers x 2 half-packets (64B) = 128 poll slots, waves
//    1-2 (h) / 3-4 (v) -- indexing identical to the 128-WG version.
//  - critical-path order per R6: z-dot -> publish v -> i/o/f dots overlap
//    the v flight -> poll v -> u-dot -> publish h.
// Rationale: per-step time = max over WGs of jittery arrival; halving the
// WG count halves the straggler population and halves poll fan-in/LLC
// pressure (a jitter source).
__global__ __launch_bounds__(WGT) void scan_kernel(
    const float* __restrict__ Wh, const float* __restrict__ bh,
    const float* __restrict__ Wum, const float* __restrict__ bum,
    const float* __restrict__ pic, const float* __restrict__ pfc,
    const float* __restrict__ poc, const float* __restrict__ pzc,
    const float* __restrict__ Gx,
    int* h_pub, int* v_pub,
    float* __restrict__ out) {
  const int wg = blockIdx.x;
  const int tid = threadIdx.x;
  const int w = tid >> 6;      // wave id
  const int ln = tid & 63;
  const int half = ln >> 5;    // 0: dim 2w, 1: dim 2w+1
  const int lh = ln & 31;      // lane within half-wave
  const int j = wg * DPW + 2 * w + half;   // owned dim
  const bool leader = (lh == 0);           // lanes 0 and 32

  __shared__ float h_lds[MEM];
  __shared__ float v_lds[MEM];
  __shared__ float share[DPW];

  // register-resident weight slices: k = lh*4 + m*128 + e  (32 per gate)
  float wi[32], wo[32], wf[32], wz[32], wu[32];
#pragma unroll
  for (int m = 0; m < 8; ++m)
#pragma unroll
    for (int e = 0; e < 4; ++e) {
      int k = lh * 4 + m * 128 + e;
      wi[m * 4 + e] = Wh[(size_t)k * 4096 + 0 * MEM + j];
      wo[m * 4 + e] = Wh[(size_t)k * 4096 + 1 * MEM + j];
      wf[m * 4 + e] = Wh[(size_t)k * 4096 + 2 * MEM + j];
      wz[m * 4 + e] = Wh[(size_t)k * 4096 + 3 * MEM + j];
      wu[m * 4 + e] = Wum[(size_t)k * MEM + j];
    }

  float b_i = 0, b_o = 0, b_f = 0, b_z = 0, b_u = 0;
  float p_i = 0, p_f = 0, p_o = 0, p_z = 0;
  if (leader) {
    b_i = bh[0 * MEM + j]; b_o = bh[1 * MEM + j];
    b_f = bh[2 * MEM + j]; b_z = bh[3 * MEM + j];
    b_u = bum[j];
    p_i = pic[j]; p_f = pfc[j]; p_o = poc[j]; p_z = pzc[j];
  }

  // leader Gx register double-buffer: g_* = step t (ready), n_* = step t+1
  float g_i = 0, g_o = 0, g_f = 0, g_z = 0, g_u = 0;
  float n_i = 0, n_o = 0, n_f = 0, n_z = 0, n_u = 0;
  if (leader) {
    g_i = Gx[j];           g_o = Gx[MEM + j];     g_f = Gx[2 * MEM + j];
    g_z = Gx[3 * MEM + j]; g_u = Gx[4 * MEM + j];
  }

  float c = 0.f, hmax = -1e30f;
  float i_keep = 0, f_keep = 0, oh_keep = 0, gux_keep = 0;

  for (int t = 0; t < NNODE; ++t) {
    // prefetch next step's Gx scalars (off critical path; lands during step)
    if (leader && t + 1 < NNODE) {
      const float* gx = Gx + (size_t)(t + 1) * GX_COLS;
      n_i = gx[j];           n_o = gx[MEM + j];     n_f = gx[2 * MEM + j];
      n_z = gx[3 * MEM + j]; n_u = gx[4 * MEM + j];
    }

    // ---- poll+stage h(t) (waves 1-2), tag == t ----
    if (tid >= 64 && tid < 192) {
      const int idx = tid - 64;  // producer half-packet: WG idx>>1, half idx&1
      float4 lo, hi;
      poll_pairs(h_pub + (t & 1) * PUBI + idx * 16, t, lo, hi);
      *(float4*)&h_lds[idx * 8] = lo;
      *(float4*)&h_lds[idx * 8 + 4] = hi;
    }
    __syncthreads();                             // S1: h_lds ready

    // pull h slice into registers (single read of h_lds per step)
    float hreg[32];
#pragma unroll
    for (int m = 0; m < 8; ++m) {
      float4 hv = *(const float4*)&h_lds[m * 128 + lh * 4];
      hreg[m * 4 + 0] = hv.x; hreg[m * 4 + 1] = hv.y;
      hreg[m * 4 + 2] = hv.z; hreg[m * 4 + 3] = hv.w;
    }

    // ---- z gate first: the only input to v ----
    float sz = 0;
#pragma unroll
    for (int q = 0; q < 32; ++q) sz += hreg[q] * wz[q];
#pragma unroll
    for (int off = 16; off >= 1; off >>= 1) sz += __shfl_down(sz, off, 32);
    if (leader) {
      float zv = fsig(g_z + sz + b_z + p_z * c);
      share[2 * w + half] = zv * ftanh(c);
    }
    __syncthreads();                             // S2: share has v slice

    if (tid < DPW)   // single wave-coalesced 128B publish (invariant!)
      store_pair(v_pub + (t & 1) * PUBI + wg * 32 + tid * 2, share[tid], t + 1);

    // ---- i/o/f dots: overlapped with the v packet's flight ----
    float si = 0, so = 0, sf = 0;
#pragma unroll
    for (int q = 0; q < 32; ++q) {
      si += hreg[q] * wi[q]; so += hreg[q] * wo[q]; sf += hreg[q] * wf[q];
    }
#pragma unroll
    for (int off = 16; off >= 1; off >>= 1) {
      si += __shfl_down(si, off, 32); so += __shfl_down(so, off, 32);
      sf += __shfl_down(sf, off, 32);
    }
    if (leader) {
      i_keep = fsig(g_i + si + b_i + p_i * c);
      f_keep = fsig(g_f + sf + b_f + p_f * c);
      oh_keep = g_o + so + b_o;
      gux_keep = g_u;
    }

    // ---- poll+stage v(t) (waves 3-4), tag == t+1 ----
    if (tid >= 192 && tid < 320) {
      const int idx = tid - 192;
      float4 lo, hi;
      poll_pairs(v_pub + (t & 1) * PUBI + idx * 16, t + 1, lo, hi);
      *(float4*)&v_lds[idx * 8] = lo;
      *(float4*)&v_lds[idx * 8 + 4] = hi;
    }
    __syncthreads();                             // S3: v_lds ready

    float sm = 0;
#pragma unroll
    for (int m = 0; m < 8; ++m) {
      float4 vv4 = *(const float4*)&v_lds[m * 128 + lh * 4];
      sm += vv4.x * wu[m * 4 + 0] + vv4.y * wu[m * 4 + 1] +
            vv4.z * wu[m * 4 + 2] + vv4.w * wu[m * 4 + 3];
    }
#pragma unroll
    for (int off = 16; off >= 1; off >>= 1) sm += __shfl_down(sm, off, 32);
    if (leader) {
      float uv = ftanh(gux_keep + sm + b_u);
      float cn = i_keep * uv + f_keep * c;
      float ov = fsig(oh_keep + p_o * cn);
      float hn = ov * ftanh(cn);
      c = cn;
      hmax = fmaxf(hmax, hn);
      share[2 * w + half] = hn;
      // rotate Gx prefetch buffers for next step
      g_i = n_i; g_o = n_o; g_f = n_f; g_z = n_z; g_u = n_u;
    }
    __syncthreads();                             // S4: share has h slice

    if (tid < DPW)   // single wave-coalesced 128B publish (invariant!)
      store_pair(h_pub + ((t + 1) & 1) * PUBI + wg * 32 + tid * 2,
                 share[tid], t + 1);
  }

  if (leader) out[j] = hmax;
}

extern "C" void kernel_launch(void* const* d_in, const int* in_sizes, int n_in,
                              void* d_out, int out_size, void* d_ws, size_t ws_size,
                              hipStream_t stream) {
  const float* inputs = (const float*)d_in[0];
  const float* Wx  = (const float*)d_in[1];
  const float* bx  = (const float*)d_in[2];
  const float* Wh  = (const float*)d_in[3];
  const float* bh  = (const float*)d_in[4];
  const float* Wum = (const float*)d_in[5];
  const float* bum = (const float*)d_in[6];
  const float* pic = (const float*)d_in[7];
  const float* pfc = (const float*)d_in[8];
  const float* poc = (const float*)d_in[9];
  const float* pzc = (const float*)d_in[10];
  float* out = (float*)d_out;

  // ws: Gx (2048*5120 f32) | h_pub (2*PUBI ints) | v_pub (2*PUBI ints)
  float* Gx = (float*)d_ws;
  int* h_pub = (int*)(Gx + (size_t)NNODE * GX_COLS);
  int* v_pub = h_pub + 2 * PUBI;

  init_ctrl<<<1, 256, 0, stream>>>(h_pub, v_pub);
  gemm_gx<<<dim3(GX_COLS / 128, NNODE / 128), 256, 0, stream>>>(inputs, Wx, bx, Gx);
  scan_kernel<<<NWG, WGT, 0, stream>>>(Wh, bh, Wum, bum, pic, pfc, poc, pzc,
                                       Gx, h_pub, v_pub, out);
}